// Round 9
// baseline (811.678 us; speedup 1.0000x reference)
//
#include <hip/hip_runtime.h>
#include <hip/hip_bf16.h>

// GraphNet B=64,N=128,H=32,HE=64,OE=32,E_IN=66, 4 mp steps.
// Edge layer1 pre-act = P1[b,i,:] + P2[b,j,:] + dist*W1[64,:] + int*W1[65,:]
// dist via Gram: dist^2 = n_i + n_j - 2*dot.
// Round-9: edge2's wave-uniform W2'/w64/w65/b2'/P1 reads moved off the LDS pipe
// onto the SCALAR path: k_fold pre-folds BN1 into wf[] in global (K$-resident),
// edge2 reads via block-uniform pointers (+readfirstlane for P1 rows) -> s_load.
// Main-loop LDS insts/chunk: 34 -> 0. Node phase = round-8 fused k_nodeF
// (software grid barrier, validated).

#define ALPHA 0.1f
#define BN_EPS 1e-5f
#define LRELU(v) ((v) > 0.f ? (v) : ALPHA * (v))

// ---------------- pad + step-0 prep: xc, P1, P2, nbuf ----------------
__global__ __launch_bounds__(128) void k_pad_prep(const float* __restrict__ x,
                                                  const float* __restrict__ W1,
                                                  const float* __restrict__ b1,
                                                  float* __restrict__ xc,
                                                  float* __restrict__ P1,
                                                  float* __restrict__ P2,
                                                  float2* __restrict__ nbuf) {
    __shared__ float w1s[384];   // rows 0..2 and 32..34 of W1
    __shared__ float b1s[64];
    const int tid = threadIdx.x;
    for (int u = tid; u < 384; u += 128) {
        const int r = u >> 6, c = u & 63;
        const int srow = (r < 3) ? r : (32 + r - 3);
        w1s[u] = W1[srow * 64 + c];
    }
    if (tid < 64) b1s[tid] = b1[tid];
    const int row = blockIdx.x * 128 + tid;
    const float x0 = x[row * 3 + 0], x1 = x[row * 3 + 1], x2 = x[row * 3 + 2];
    __syncthreads();
    float4* xp = (float4*)(xc + row * 32);
    xp[0] = make_float4(x0, x1, x2, 0.f);
    const float4 z4 = make_float4(0.f, 0.f, 0.f, 0.f);
#pragma unroll
    for (int u = 1; u < 8; ++u) xp[u] = z4;
    nbuf[row] = make_float2(x0 * x0 + x1 * x1 + x2 * x2, 0.f);
    float* p1p = P1 + row * 64;
    float* p2p = P2 + row * 64;
#pragma unroll
    for (int c = 0; c < 64; ++c) {
        p1p[c] = b1s[c] + x0 * w1s[c] + x1 * w1s[64 + c] + x2 * w1s[128 + c];
        p2p[c] = x0 * w1s[192 + c] + x1 * w1s[256 + c] + x2 * w1s[320 + c];
    }
}

// ---------------- edge pass 1: BN1 stats of lrelu(layer1) ----------------
__global__ __launch_bounds__(256) void k_edge1(const float* __restrict__ xc,
                                               const float2* __restrict__ nbuf,
                                               const float* __restrict__ P1,
                                               const float* __restrict__ P2,
                                               const float* __restrict__ W1,
                                               float* __restrict__ stA) {
    __shared__ float xs[128 * 33];
    __shared__ float ddot[1024];
    __shared__ float2 nls[128];
    __shared__ float red[512];
    const int tid = threadIdx.x;
    const int b = blockIdx.x >> 4;
    const int ibase = (blockIdx.x & 15) * 8;
    const float* xg = xc + b * 4096;
    for (int u = tid; u < 4096; u += 256) xs[(u >> 5) * 33 + (u & 31)] = xg[u];
    if (tid < 128) nls[tid] = nbuf[b * 128 + tid];
    __syncthreads();
    {   // dot phase: ddot[il][j] = dot(x[ibase+il,0:31], x[j,0:31])
        const int il = tid >> 5, jb = tid & 31;
        const float* xi = &xs[(ibase + il) * 33];
        float xi_r[31];
#pragma unroll
        for (int k = 0; k < 31; ++k) xi_r[k] = xi[k];
        for (int q = 0; q < 4; ++q) {
            const int j = jb + 32 * q;
            const float* xj = &xs[j * 33];
            float d = 0.f;
#pragma unroll
            for (int k = 0; k < 31; ++k) d = fmaf(xi_r[k], xj[k], d);
            ddot[il * 128 + j] = d;
        }
    }
    __syncthreads();
    const int cg_ = tid & 3, eg = tid >> 2;
    float w64r[16], w65r[16];
    {
        const float* wg4 = W1 + 64 * 64 + cg_ * 16;
        const float* wg5 = W1 + 65 * 64 + cg_ * 16;
#pragma unroll
        for (int u = 0; u < 4; ++u) {
            float4 v = *(const float4*)(wg4 + u * 4);
            w64r[4*u] = v.x; w64r[4*u+1] = v.y; w64r[4*u+2] = v.z; w64r[4*u+3] = v.w;
            float4 w = *(const float4*)(wg5 + u * 4);
            w65r[4*u] = w.x; w65r[4*u+1] = w.y; w65r[4*u+2] = w.z; w65r[4*u+3] = w.w;
        }
    }
    float sum[16], sq[16];
#pragma unroll
    for (int u = 0; u < 16; ++u) { sum[u] = 0.f; sq[u] = 0.f; }
    for (int ei = 0; ei < 16; ++ei) {
        const int eid = eg + 64 * ei;          // il wave-uniform
        const int il = eid >> 7, j = eid & 127;
        const float2 nj = nls[j];
        const float2 ni = nls[ibase + il];
        const float dot = ddot[il * 128 + j];
        const float dist = sqrtf(fmaxf(ni.x + nj.x - 2.f * dot, 0.f));
        const float itf = 1.f - (nj.y - ni.y);
        const int prow = __builtin_amdgcn_readfirstlane((b * 128 + ibase + il) * 64) + cg_ * 16;
        const float* p2row = P2 + (b * 128 + j) * 64 + cg_ * 16;
#pragma unroll
        for (int u = 0; u < 4; ++u) {
            const float4 p1v = *(const float4*)(P1 + prow + u * 4);
            const float4 p2v = *(const float4*)(p2row + u * 4);
            float y0 = fmaf(itf, w65r[4*u+0], fmaf(dist, w64r[4*u+0], p1v.x + p2v.x));
            float y1 = fmaf(itf, w65r[4*u+1], fmaf(dist, w64r[4*u+1], p1v.y + p2v.y));
            float y2 = fmaf(itf, w65r[4*u+2], fmaf(dist, w64r[4*u+2], p1v.z + p2v.z));
            float y3 = fmaf(itf, w65r[4*u+3], fmaf(dist, w64r[4*u+3], p1v.w + p2v.w));
            y0 = LRELU(y0); y1 = LRELU(y1); y2 = LRELU(y2); y3 = LRELU(y3);
            sum[4*u+0] += y0; sq[4*u+0] += y0 * y0;
            sum[4*u+1] += y1; sq[4*u+1] += y1 * y1;
            sum[4*u+2] += y2; sq[4*u+2] += y2 * y2;
            sum[4*u+3] += y3; sq[4*u+3] += y3 * y3;
        }
    }
#pragma unroll
    for (int u = 0; u < 16; ++u) {
        float s = sum[u], q = sq[u];
#pragma unroll
        for (int m = 4; m < 64; m <<= 1) { s += __shfl_xor(s, m, 64); q += __shfl_xor(q, m, 64); }
        sum[u] = s; sq[u] = q;
    }
    const int l = tid & 63, w = tid >> 6;
#pragma unroll
    for (int k = 0; k < 16; ++k) {
        if ((l >> 2) == k) {
            red[w * 128 + cg_ * 32 + k] = sum[k];
            red[w * 128 + cg_ * 32 + 16 + k] = sq[k];
        }
    }
    __syncthreads();
    if (tid < 128) {
        const float t = red[tid] + red[128 + tid] + red[256 + tid] + red[384 + tid];
        const int cgf = tid >> 5, r = tid & 31;
        if (r < 16) atomicAdd(stA + cgf * 16 + r, t);
        else        atomicAdd(stA + 64 + cgf * 16 + (r - 16), t);
    }
}

// ---------------- fold BN1 into wf: [w64(64) | w65(64) | b2'(32+pad32) | W2'(2048)] ----
__global__ __launch_bounds__(256) void k_fold(const float* __restrict__ stA,
                                              const float* __restrict__ g1,
                                              const float* __restrict__ bt1,
                                              const float* __restrict__ W1,
                                              const float* __restrict__ W2,
                                              const float* __restrict__ b2g,
                                              float* __restrict__ wf) {
    __shared__ float s1[64], t1[64];
    const int tid = threadIdx.x;
    if (tid < 64) {
        const float ic = 1.f / 1048576.f;
        const float mu = stA[tid] * ic;
        const float var = stA[64 + tid] * ic - mu * mu;
        const float sv = g1[tid] * rsqrtf(var + BN_EPS);
        s1[tid] = sv;
        t1[tid] = bt1[tid] - mu * sv;
        wf[tid] = W1[64 * 64 + tid];
        wf[64 + tid] = W1[65 * 64 + tid];
    }
    __syncthreads();
    for (int u = tid; u < 2048; u += 256) wf[192 + u] = W2[u] * s1[u >> 5];
    if (tid < 32) {
        float acc = b2g[tid];
#pragma unroll
        for (int k = 0; k < 64; ++k) acc = fmaf(t1[k], W2[k * 32 + tid], acc);
        wf[128 + tid] = acc;
    }
}

// ---------------- edge pass 2: layer1 + GEMM2(W2') + aggregate ----
// wave w: il0=w, il1=w+4; lane l: j=l, l+64 (4 edges/lane, one k-loop).
// All wave-uniform operands (wf, P1 rows) read via scalar path; no LDS in loop.
__global__ __launch_bounds__(256) void k_edge2(const float* __restrict__ xc,
                                               const float2* __restrict__ nbuf,
                                               const float* __restrict__ P1,
                                               const float* __restrict__ P2,
                                               const float* __restrict__ wf,
                                               float* __restrict__ stB,
                                               float* __restrict__ aggp) {
    __shared__ float xs[128 * 33];
    __shared__ float ddot[1024];
    __shared__ float2 nls[128];
    __shared__ float aggl[256];
    __shared__ float redq[128];
    const int tid = threadIdx.x;
    const int b = blockIdx.x >> 4;
    const int ibase = (blockIdx.x & 15) * 8;
    const float* xg = xc + b * 4096;
    for (int u = tid; u < 4096; u += 256) xs[(u >> 5) * 33 + (u & 31)] = xg[u];
    if (tid < 128) nls[tid] = nbuf[b * 128 + tid];
    __syncthreads();
    {   // dot phase
        const int il = tid >> 5, jb = tid & 31;
        const float* xi = &xs[(ibase + il) * 33];
        float xi_r[31];
#pragma unroll
        for (int k = 0; k < 31; ++k) xi_r[k] = xi[k];
        for (int q = 0; q < 4; ++q) {
            const int j = jb + 32 * q;
            const float* xj = &xs[j * 33];
            float d = 0.f;
#pragma unroll
            for (int k = 0; k < 31; ++k) d = fmaf(xi_r[k], xj[k], d);
            ddot[il * 128 + j] = d;
        }
    }
    __syncthreads();
    const int w = tid >> 6, l = tid & 63;
    const int il0 = w, il1 = w + 4;
    const float2 ni0 = nls[ibase + il0];
    const float2 ni1 = nls[ibase + il1];
    const float2 njA = nls[l];
    const float2 njB = nls[l + 64];
    const float dist00 = sqrtf(fmaxf(ni0.x + njA.x - 2.f * ddot[il0 * 128 + l], 0.f));
    const float dist01 = sqrtf(fmaxf(ni0.x + njB.x - 2.f * ddot[il0 * 128 + l + 64], 0.f));
    const float dist10 = sqrtf(fmaxf(ni1.x + njA.x - 2.f * ddot[il1 * 128 + l], 0.f));
    const float dist11 = sqrtf(fmaxf(ni1.x + njB.x - 2.f * ddot[il1 * 128 + l + 64], 0.f));
    const float itf00 = 1.f - (njA.y - ni0.y);
    const float itf01 = 1.f - (njB.y - ni0.y);
    const float itf10 = 1.f - (njA.y - ni1.y);
    const float itf11 = 1.f - (njB.y - ni1.y);
    const float* p2rA = P2 + (b * 128 + l) * 64;
    const float* p2rB = P2 + (b * 128 + l + 64) * 64;
    // wave-uniform P1 row pointers (scalar path)
    const float* p1r0 = P1 + __builtin_amdgcn_readfirstlane((b * 128 + ibase + il0) * 64);
    const float* p1r1 = P1 + __builtin_amdgcn_readfirstlane((b * 128 + ibase + il1) * 64);
    const float* w2f = wf + 192;
    float z00[32], z01[32], z10[32], z11[32];
#pragma unroll
    for (int c0 = 0; c0 < 32; c0 += 4) {
        const float4 bv = *(const float4*)(wf + 128 + c0);
        z00[c0+0] = bv.x; z00[c0+1] = bv.y; z00[c0+2] = bv.z; z00[c0+3] = bv.w;
        z01[c0+0] = bv.x; z01[c0+1] = bv.y; z01[c0+2] = bv.z; z01[c0+3] = bv.w;
        z10[c0+0] = bv.x; z10[c0+1] = bv.y; z10[c0+2] = bv.z; z10[c0+3] = bv.w;
        z11[c0+0] = bv.x; z11[c0+1] = bv.y; z11[c0+2] = bv.z; z11[c0+3] = bv.w;
    }
#pragma unroll 1
    for (int k0 = 0; k0 < 64; k0 += 4) {
        const float4 pA = *(const float4*)(p2rA + k0);
        const float4 pB = *(const float4*)(p2rB + k0);
        const float4 p10 = *(const float4*)(p1r0 + k0);
        const float4 p11 = *(const float4*)(p1r1 + k0);
        const float4 wa = *(const float4*)(wf + k0);
        const float4 wb = *(const float4*)(wf + 64 + k0);
        float y00 = fmaf(itf00, wb.x, fmaf(dist00, wa.x, p10.x + pA.x));
        float y01 = fmaf(itf00, wb.y, fmaf(dist00, wa.y, p10.y + pA.y));
        float y02 = fmaf(itf00, wb.z, fmaf(dist00, wa.z, p10.z + pA.z));
        float y03 = fmaf(itf00, wb.w, fmaf(dist00, wa.w, p10.w + pA.w));
        float y10 = fmaf(itf01, wb.x, fmaf(dist01, wa.x, p10.x + pB.x));
        float y11 = fmaf(itf01, wb.y, fmaf(dist01, wa.y, p10.y + pB.y));
        float y12 = fmaf(itf01, wb.z, fmaf(dist01, wa.z, p10.z + pB.z));
        float y13 = fmaf(itf01, wb.w, fmaf(dist01, wa.w, p10.w + pB.w));
        float y20 = fmaf(itf10, wb.x, fmaf(dist10, wa.x, p11.x + pA.x));
        float y21 = fmaf(itf10, wb.y, fmaf(dist10, wa.y, p11.y + pA.y));
        float y22 = fmaf(itf10, wb.z, fmaf(dist10, wa.z, p11.z + pA.z));
        float y23 = fmaf(itf10, wb.w, fmaf(dist10, wa.w, p11.w + pA.w));
        float y30 = fmaf(itf11, wb.x, fmaf(dist11, wa.x, p11.x + pB.x));
        float y31 = fmaf(itf11, wb.y, fmaf(dist11, wa.y, p11.y + pB.y));
        float y32 = fmaf(itf11, wb.z, fmaf(dist11, wa.z, p11.z + pB.z));
        float y33 = fmaf(itf11, wb.w, fmaf(dist11, wa.w, p11.w + pB.w));
        y00 = LRELU(y00); y01 = LRELU(y01); y02 = LRELU(y02); y03 = LRELU(y03);
        y10 = LRELU(y10); y11 = LRELU(y11); y12 = LRELU(y12); y13 = LRELU(y13);
        y20 = LRELU(y20); y21 = LRELU(y21); y22 = LRELU(y22); y23 = LRELU(y23);
        y30 = LRELU(y30); y31 = LRELU(y31); y32 = LRELU(y32); y33 = LRELU(y33);
        const float* wk0 = w2f + (k0 + 0) * 32;
        const float* wk1 = w2f + (k0 + 1) * 32;
        const float* wk2 = w2f + (k0 + 2) * 32;
        const float* wk3 = w2f + (k0 + 3) * 32;
#pragma unroll
        for (int c0 = 0; c0 < 32; c0 += 4) {
            const float4 wv0 = *(const float4*)(wk0 + c0);
            const float4 wv1 = *(const float4*)(wk1 + c0);
            const float4 wv2 = *(const float4*)(wk2 + c0);
            const float4 wv3 = *(const float4*)(wk3 + c0);
            z00[c0+0] = fmaf(y03, wv3.x, fmaf(y02, wv2.x, fmaf(y01, wv1.x, fmaf(y00, wv0.x, z00[c0+0]))));
            z00[c0+1] = fmaf(y03, wv3.y, fmaf(y02, wv2.y, fmaf(y01, wv1.y, fmaf(y00, wv0.y, z00[c0+1]))));
            z00[c0+2] = fmaf(y03, wv3.z, fmaf(y02, wv2.z, fmaf(y01, wv1.z, fmaf(y00, wv0.z, z00[c0+2]))));
            z00[c0+3] = fmaf(y03, wv3.w, fmaf(y02, wv2.w, fmaf(y01, wv1.w, fmaf(y00, wv0.w, z00[c0+3]))));
            z01[c0+0] = fmaf(y13, wv3.x, fmaf(y12, wv2.x, fmaf(y11, wv1.x, fmaf(y10, wv0.x, z01[c0+0]))));
            z01[c0+1] = fmaf(y13, wv3.y, fmaf(y12, wv2.y, fmaf(y11, wv1.y, fmaf(y10, wv0.y, z01[c0+1]))));
            z01[c0+2] = fmaf(y13, wv3.z, fmaf(y12, wv2.z, fmaf(y11, wv1.z, fmaf(y10, wv0.z, z01[c0+2]))));
            z01[c0+3] = fmaf(y13, wv3.w, fmaf(y12, wv2.w, fmaf(y11, wv1.w, fmaf(y10, wv0.w, z01[c0+3]))));
            z10[c0+0] = fmaf(y23, wv3.x, fmaf(y22, wv2.x, fmaf(y21, wv1.x, fmaf(y20, wv0.x, z10[c0+0]))));
            z10[c0+1] = fmaf(y23, wv3.y, fmaf(y22, wv2.y, fmaf(y21, wv1.y, fmaf(y20, wv0.y, z10[c0+1]))));
            z10[c0+2] = fmaf(y23, wv3.z, fmaf(y22, wv2.z, fmaf(y21, wv1.z, fmaf(y20, wv0.z, z10[c0+2]))));
            z10[c0+3] = fmaf(y23, wv3.w, fmaf(y22, wv2.w, fmaf(y21, wv1.w, fmaf(y20, wv0.w, z10[c0+3]))));
            z11[c0+0] = fmaf(y33, wv3.x, fmaf(y32, wv2.x, fmaf(y31, wv1.x, fmaf(y30, wv0.x, z11[c0+0]))));
            z11[c0+1] = fmaf(y33, wv3.y, fmaf(y32, wv2.y, fmaf(y31, wv1.y, fmaf(y30, wv0.y, z11[c0+1]))));
            z11[c0+2] = fmaf(y33, wv3.z, fmaf(y32, wv2.z, fmaf(y31, wv1.z, fmaf(y30, wv0.z, z11[c0+2]))));
            z11[c0+3] = fmaf(y33, wv3.w, fmaf(y32, wv2.w, fmaf(y31, wv1.w, fmaf(y30, wv0.w, z11[c0+3]))));
        }
    }
    // per-c: lrelu, combine, wave-reduce, store
#pragma unroll
    for (int c = 0; c < 32; ++c) {
        const float zz00 = LRELU(z00[c]);
        const float zz01 = LRELU(z01[c]);
        const float zz10 = LRELU(z10[c]);
        const float zz11 = LRELU(z11[c]);
        float rz0 = zz00 + zz01;
        float rz1 = zz10 + zz11;
        float rq = zz00 * zz00 + zz01 * zz01 + zz10 * zz10 + zz11 * zz11;
#pragma unroll
        for (int m = 1; m < 64; m <<= 1) {
            rz0 += __shfl_xor(rz0, m, 64);
            rz1 += __shfl_xor(rz1, m, 64);
            rq  += __shfl_xor(rq, m, 64);
        }
        if (l == c) {
            aggl[il0 * 32 + c] = rz0;
            aggl[il1 * 32 + c] = rz1;
            redq[w * 32 + c] = rq;
        }
    }
    __syncthreads();
    {
        const int il2 = tid >> 5, c2 = tid & 31;
        aggp[(b * 128 + ibase + il2) * 32 + c2] = aggl[il2 * 32 + c2];
    }
    if (tid < 32) {
        float s = 0.f;
#pragma unroll
        for (int il3 = 0; il3 < 8; ++il3) s += aggl[il3 * 32 + tid];
        atomicAdd(stB + tid, s);
        const float qq = redq[tid] + redq[32 + tid] + redq[64 + tid] + redq[96 + tid];
        atomicAdd(stB + 32 + tid, qq);
    }
}

// ---------------- software grid barrier (all blocks co-resident) ----------------
__device__ __forceinline__ void gbar(unsigned int* ctr, unsigned int target) {
    __syncthreads();
    if (threadIdx.x == 0) {
        __hip_atomic_fetch_add(ctr, 1u, __ATOMIC_ACQ_REL, __HIP_MEMORY_SCOPE_AGENT);
        while (__hip_atomic_load(ctr, __ATOMIC_ACQUIRE, __HIP_MEMORY_SCOPE_AGENT) < target) {
            __builtin_amdgcn_s_sleep(2);
        }
    }
    __syncthreads();
}

// ---------------- fused node MLP: L1 -> BN -> L2 -> BN -> tanh(Wu) + prep ----
__global__ __launch_bounds__(256) void k_nodeF(
    const float* __restrict__ aggp, const float* __restrict__ xc,
    const float* __restrict__ W0, const float* __restrict__ b0,
    const float* __restrict__ stB, const float* __restrict__ g2, const float* __restrict__ bt2,
    const float* __restrict__ W1m, const float* __restrict__ b1m,
    float* __restrict__ stC, const float* __restrict__ gC, const float* __restrict__ btC,
    const float* __restrict__ W2m, const float* __restrict__ b2m,
    float* __restrict__ stD, const float* __restrict__ gD, const float* __restrict__ btD,
    float* __restrict__ xout,
    const float* __restrict__ W1n, const float* __restrict__ b1n,
    float* __restrict__ P1, float* __restrict__ P2, float2* __restrict__ nbuf,
    unsigned int* __restrict__ bar, int doPrep)
{
    __shared__ float w0s[2048];
    __shared__ float wms[1024];
    __shared__ float wus[1024];
    __shared__ float w1s[4096];
    __shared__ float b0s[32], s2s[32], t2s[32];
    __shared__ float bms[32], sCs[32], tCs[32];
    __shared__ float bus[32], sDs[32], tDs[32];
    __shared__ float b1s[64];
    __shared__ float red[256];
    const int tid = threadIdx.x;
    const int row = blockIdx.x * 256 + tid;
    for (int k = tid; k < 2048; k += 256) w0s[k] = W0[k];
    for (int k = tid; k < 1024; k += 256) { wms[k] = W1m[k]; wus[k] = W2m[k]; }
    if (doPrep) {
        for (int k = tid; k < 4096; k += 256) w1s[k] = W1n[k];
        if (tid < 64) b1s[tid] = b1n[tid];
    }
    if (tid < 32) {
        b0s[tid] = b0[tid]; bms[tid] = b1m[tid]; bus[tid] = b2m[tid];
        const float ic = 1.f / 1048576.f;
        const float mu = stB[tid] * ic;
        const float var = stB[32 + tid] * ic - mu * mu;
        const float sv = g2[tid] * rsqrtf(var + BN_EPS);
        s2s[tid] = sv; t2s[tid] = bt2[tid] - mu * sv;
    }
    __syncthreads();
    float h[64];
    {
        const float4* ap = (const float4*)(aggp + row * 32);
        const float4* xp = (const float4*)(xc + row * 32);
#pragma unroll
        for (int u = 0; u < 8; ++u) {
            const float4 a = ap[u];
            h[4*u+0] = fmaf(s2s[4*u+0], a.x, 128.f * t2s[4*u+0]);
            h[4*u+1] = fmaf(s2s[4*u+1], a.y, 128.f * t2s[4*u+1]);
            h[4*u+2] = fmaf(s2s[4*u+2], a.z, 128.f * t2s[4*u+2]);
            h[4*u+3] = fmaf(s2s[4*u+3], a.w, 128.f * t2s[4*u+3]);
            const float4 xv = xp[u];
            h[32+4*u+0] = xv.x; h[32+4*u+1] = xv.y; h[32+4*u+2] = xv.z; h[32+4*u+3] = xv.w;
        }
    }
    float v[32];
#pragma unroll
    for (int o0 = 0; o0 < 32; o0 += 4) {
        float z0 = b0s[o0], z1 = b0s[o0+1], z2 = b0s[o0+2], z3 = b0s[o0+3];
#pragma unroll
        for (int k = 0; k < 64; ++k) {
            const float4 wv = *(const float4*)&w0s[k * 32 + o0];
            const float hv = h[k];
            z0 = fmaf(hv, wv.x, z0); z1 = fmaf(hv, wv.y, z1);
            z2 = fmaf(hv, wv.z, z2); z3 = fmaf(hv, wv.w, z3);
        }
        v[o0] = LRELU(z0); v[o0+1] = LRELU(z1); v[o0+2] = LRELU(z2); v[o0+3] = LRELU(z3);
    }
    {
        float sarr[32], qarr[32];
#pragma unroll
        for (int o = 0; o < 32; ++o) {
            float s = v[o], q = v[o] * v[o];
#pragma unroll
            for (int m = 1; m < 64; m <<= 1) { s += __shfl_xor(s, m, 64); q += __shfl_xor(q, m, 64); }
            sarr[o] = s; qarr[o] = q;
        }
        const int lane = tid & 63, wid = tid >> 6;
        if (lane == 0) {
#pragma unroll
            for (int o = 0; o < 32; ++o) { red[wid * 64 + o] = sarr[o]; red[wid * 64 + 32 + o] = qarr[o]; }
        }
        __syncthreads();
        if (tid < 64) {
            const float t = red[tid] + red[64 + tid] + red[128 + tid] + red[192 + tid];
            atomicAdd(stC + tid, t);
        }
    }
    gbar(bar + 0, 32);
    if (tid < 32) {
        const float ic = 1.f / 8192.f;
        const float mu = __hip_atomic_load(stC + tid, __ATOMIC_RELAXED, __HIP_MEMORY_SCOPE_AGENT) * ic;
        const float sq = __hip_atomic_load(stC + 32 + tid, __ATOMIC_RELAXED, __HIP_MEMORY_SCOPE_AGENT) * ic;
        const float var = sq - mu * mu;
        const float sv = gC[tid] * rsqrtf(var + BN_EPS);
        sCs[tid] = sv; tCs[tid] = btC[tid] - mu * sv;
    }
    __syncthreads();
    float hh[32];
#pragma unroll
    for (int c = 0; c < 32; ++c) hh[c] = fmaf(sCs[c], v[c], tCs[c]);
    float v2[32];
#pragma unroll
    for (int o0 = 0; o0 < 32; o0 += 4) {
        float z0 = bms[o0], z1 = bms[o0+1], z2 = bms[o0+2], z3 = bms[o0+3];
#pragma unroll
        for (int k = 0; k < 32; ++k) {
            const float4 wv = *(const float4*)&wms[k * 32 + o0];
            const float hv = hh[k];
            z0 = fmaf(hv, wv.x, z0); z1 = fmaf(hv, wv.y, z1);
            z2 = fmaf(hv, wv.z, z2); z3 = fmaf(hv, wv.w, z3);
        }
        v2[o0] = LRELU(z0); v2[o0+1] = LRELU(z1); v2[o0+2] = LRELU(z2); v2[o0+3] = LRELU(z3);
    }
    {
        float sarr[32], qarr[32];
#pragma unroll
        for (int o = 0; o < 32; ++o) {
            float s = v2[o], q = v2[o] * v2[o];
#pragma unroll
            for (int m = 1; m < 64; m <<= 1) { s += __shfl_xor(s, m, 64); q += __shfl_xor(q, m, 64); }
            sarr[o] = s; qarr[o] = q;
        }
        const int lane = tid & 63, wid = tid >> 6;
        __syncthreads();
        if (lane == 0) {
#pragma unroll
            for (int o = 0; o < 32; ++o) { red[wid * 64 + o] = sarr[o]; red[wid * 64 + 32 + o] = qarr[o]; }
        }
        __syncthreads();
        if (tid < 64) {
            const float t = red[tid] + red[64 + tid] + red[128 + tid] + red[192 + tid];
            atomicAdd(stD + tid, t);
        }
    }
    gbar(bar + 1, 32);
    if (tid < 32) {
        const float ic = 1.f / 8192.f;
        const float mu = __hip_atomic_load(stD + tid, __ATOMIC_RELAXED, __HIP_MEMORY_SCOPE_AGENT) * ic;
        const float sq = __hip_atomic_load(stD + 32 + tid, __ATOMIC_RELAXED, __HIP_MEMORY_SCOPE_AGENT) * ic;
        const float var = sq - mu * mu;
        const float sv = gD[tid] * rsqrtf(var + BN_EPS);
        sDs[tid] = sv; tDs[tid] = btD[tid] - mu * sv;
    }
    __syncthreads();
    float h3[32];
#pragma unroll
    for (int c = 0; c < 32; ++c) h3[c] = fmaf(sDs[c], v2[c], tDs[c]);
    float xn[32];
    float* xp = xout + row * 32;
#pragma unroll
    for (int o0 = 0; o0 < 32; o0 += 4) {
        float z0 = bus[o0], z1 = bus[o0+1], z2 = bus[o0+2], z3 = bus[o0+3];
#pragma unroll
        for (int k = 0; k < 32; ++k) {
            const float4 wv = *(const float4*)&wus[k * 32 + o0];
            const float hv = h3[k];
            z0 = fmaf(hv, wv.x, z0); z1 = fmaf(hv, wv.y, z1);
            z2 = fmaf(hv, wv.z, z2); z3 = fmaf(hv, wv.w, z3);
        }
        xn[o0]   = tanhf(z0);
        xn[o0+1] = tanhf(z1);
        xn[o0+2] = tanhf(z2);
        xn[o0+3] = tanhf(z3);
        xp[o0] = xn[o0]; xp[o0+1] = xn[o0+1]; xp[o0+2] = xn[o0+2]; xp[o0+3] = xn[o0+3];
    }
    if (!doPrep) return;
    float n = 0.f;
#pragma unroll
    for (int k = 0; k < 31; ++k) n = fmaf(xn[k], xn[k], n);
    nbuf[row] = make_float2(n, xn[31]);
    float* p1p = P1 + row * 64;
    float* p2p = P2 + row * 64;
#pragma unroll
    for (int c0 = 0; c0 < 64; c0 += 4) {
        float a0 = b1s[c0], a1 = b1s[c0+1], a2 = b1s[c0+2], a3 = b1s[c0+3];
        float q0 = 0.f, q1 = 0.f, q2 = 0.f, q3 = 0.f;
#pragma unroll
        for (int k = 0; k < 32; ++k) {
            const float xv = xn[k];
            const float4 wa = *(const float4*)&w1s[k * 64 + c0];
            const float4 wb = *(const float4*)&w1s[(32 + k) * 64 + c0];
            a0 = fmaf(xv, wa.x, a0); a1 = fmaf(xv, wa.y, a1);
            a2 = fmaf(xv, wa.z, a2); a3 = fmaf(xv, wa.w, a3);
            q0 = fmaf(xv, wb.x, q0); q1 = fmaf(xv, wb.y, q1);
            q2 = fmaf(xv, wb.z, q2); q3 = fmaf(xv, wb.w, q3);
        }
        p1p[c0] = a0; p1p[c0+1] = a1; p1p[c0+2] = a2; p1p[c0+3] = a3;
        p2p[c0] = q0; p2p[c0+1] = q1; p2p[c0+2] = q2; p2p[c0+3] = q3;
    }
}

extern "C" void kernel_launch(void* const* d_in, const int* in_sizes, int n_in,
                              void* d_out, int out_size, void* d_ws, size_t ws_size,
                              hipStream_t stream) {
    const float* x    = (const float*)d_in[0];
    const float* Wah  = (const float*)d_in[1];
    const float* bah  = (const float*)d_in[2];
    const float* Wa   = (const float*)d_in[3];
    const float* ba   = (const float*)d_in[4];
    const float* g_eh = (const float*)d_in[5];
    const float* b_eh = (const float*)d_in[6];
    const float* g_e  = (const float*)d_in[7];
    const float* b_e  = (const float*)d_in[8];
    const float* Wn0  = (const float*)d_in[9];
    const float* bn0  = (const float*)d_in[10];
    const float* Wn   = (const float*)d_in[11];
    const float* bnn  = (const float*)d_in[12];
    const float* g_n  = (const float*)d_in[13];
    const float* b_n  = (const float*)d_in[14];
    const float* Wu   = (const float*)d_in[15];
    const float* bu   = (const float*)d_in[16];

    float* ws    = (float*)d_ws;
    float* xc    = ws;                 // 262144
    float* aggp  = ws + 262144;        // 262144
    float* P1    = ws + 786432;        // 524288
    float* P2    = ws + 1310720;       // 524288
    float2* nbuf = (float2*)(ws + 1835008);  // 16384 float2
    float* stats = ws + 1867776;       // 1280 (320/step)
    unsigned int* bar = (unsigned int*)(ws + 1869056);  // 16 counters
    float* wf    = ws + 1869072;       // 2240 fold buffer
    float* out   = (float*)d_out;

    hipMemsetAsync(stats, 0, (1280 + 16) * sizeof(float), stream);
    k_pad_prep<<<64, 128, 0, stream>>>(x, Wah, bah, xc, P1, P2, nbuf);

    for (int s = 0; s < 4; ++s) {
        const float* W1 = Wah + s * 66 * 64;
        const float* W2 = Wa + s * 64 * 32;
        const float* b2 = ba + s * 32;
        float* stA = stats + s * 320;
        float* stB = stA + 128;
        float* stC = stA + 192;
        float* stD = stA + 256;

        k_edge1<<<1024, 256, 0, stream>>>(xc, nbuf, P1, P2, W1, stA);
        k_fold<<<1, 256, 0, stream>>>(stA, g_eh + s * 64, b_eh + s * 64, W1, W2, b2, wf);
        k_edge2<<<1024, 256, 0, stream>>>(xc, nbuf, P1, P2, wf, stB, aggp);
        k_nodeF<<<32, 256, 0, stream>>>(aggp, xc, Wn0 + s * 2048, bn0 + s * 32,
                                        stB, g_e + s * 32, b_e + s * 32,
                                        Wn + s * 1024, bnn + s * 32,
                                        stC, g_n + s * 64, b_n + s * 64,
                                        Wu + s * 1024, bu + s * 32,
                                        stD, g_n + s * 64 + 32, b_n + s * 64 + 32,
                                        (s == 3) ? out : xc,
                                        (s < 3) ? (Wah + (s + 1) * 66 * 64) : Wah,
                                        (s < 3) ? (bah + (s + 1) * 64) : bah,
                                        P1, P2, nbuf, bar + s * 2, (s < 3) ? 1 : 0);
    }
}

// Round 11
// 660.406 us; speedup vs baseline: 1.2291x; 1.2291x over previous
//
#include <hip/hip_runtime.h>
#include <hip/hip_bf16.h>

// GraphNet B=64,N=128,H=32,HE=64,OE=32,E_IN=66, 4 mp steps.
// Edge layer1 pre-act = P1[b,i,:] + P2[b,j,:] + dist*W1[64,:] + int*W1[65,:]
// dist via Gram: dist^2 = n_i + n_j - 2*dot.
// Round-11: round-10's MFMA GEMM2 (layout verified: absmax 0.049 = pure bf16
// quant error, not layout) + SPLIT-BF16 3-product compensation: A=Ahi+Alo,
// B=Bhi+Blo (lo = bf16(x-float(hi))), acc = AhiBhi + AhiBlo + AloBhi.
// First-order quant error cancels (~256x) -> absmax back to ~0.004 floor.

#define ALPHA 0.1f
#define BN_EPS 1e-5f
#define LRELU(v) ((v) > 0.f ? (v) : ALPHA * (v))

typedef __attribute__((ext_vector_type(8))) short short8v;
typedef __attribute__((ext_vector_type(4))) float f32x4;

__device__ __forceinline__ unsigned short bf16rne(float f) {
    unsigned int u = __float_as_uint(f);
    unsigned int r = u + 0x7fffu + ((u >> 16) & 1u);
    return (unsigned short)(r >> 16);
}
__device__ __forceinline__ float bf16tof(unsigned short h) {
    return __uint_as_float(((unsigned int)h) << 16);
}

// ---------------- pad + step-0 prep: xc, P1, P2, nbuf ----------------
__global__ __launch_bounds__(128) void k_pad_prep(const float* __restrict__ x,
                                                  const float* __restrict__ W1,
                                                  const float* __restrict__ b1,
                                                  float* __restrict__ xc,
                                                  float* __restrict__ P1,
                                                  float* __restrict__ P2,
                                                  float2* __restrict__ nbuf) {
    __shared__ float w1s[384];
    __shared__ float b1s[64];
    const int tid = threadIdx.x;
    for (int u = tid; u < 384; u += 128) {
        const int r = u >> 6, c = u & 63;
        const int srow = (r < 3) ? r : (32 + r - 3);
        w1s[u] = W1[srow * 64 + c];
    }
    if (tid < 64) b1s[tid] = b1[tid];
    const int row = blockIdx.x * 128 + tid;
    const float x0 = x[row * 3 + 0], x1 = x[row * 3 + 1], x2 = x[row * 3 + 2];
    __syncthreads();
    float4* xp = (float4*)(xc + row * 32);
    xp[0] = make_float4(x0, x1, x2, 0.f);
    const float4 z4 = make_float4(0.f, 0.f, 0.f, 0.f);
#pragma unroll
    for (int u = 1; u < 8; ++u) xp[u] = z4;
    nbuf[row] = make_float2(x0 * x0 + x1 * x1 + x2 * x2, 0.f);
    float* p1p = P1 + row * 64;
    float* p2p = P2 + row * 64;
#pragma unroll
    for (int c = 0; c < 64; ++c) {
        p1p[c] = b1s[c] + x0 * w1s[c] + x1 * w1s[64 + c] + x2 * w1s[128 + c];
        p2p[c] = x0 * w1s[192 + c] + x1 * w1s[256 + c] + x2 * w1s[320 + c];
    }
}

// ---------------- edge pass 1: BN1 stats of lrelu(layer1) ----------------
__global__ __launch_bounds__(256) void k_edge1(const float* __restrict__ xc,
                                               const float2* __restrict__ nbuf,
                                               const float* __restrict__ P1,
                                               const float* __restrict__ P2,
                                               const float* __restrict__ W1,
                                               float* __restrict__ stA) {
    __shared__ float xs[128 * 33];
    __shared__ float ddot[1024];
    __shared__ float2 nls[128];
    __shared__ float red[512];
    const int tid = threadIdx.x;
    const int b = blockIdx.x >> 4;
    const int ibase = (blockIdx.x & 15) * 8;
    const float* xg = xc + b * 4096;
    for (int u = tid; u < 4096; u += 256) xs[(u >> 5) * 33 + (u & 31)] = xg[u];
    if (tid < 128) nls[tid] = nbuf[b * 128 + tid];
    __syncthreads();
    {
        const int il = tid >> 5, jb = tid & 31;
        const float* xi = &xs[(ibase + il) * 33];
        float xi_r[31];
#pragma unroll
        for (int k = 0; k < 31; ++k) xi_r[k] = xi[k];
        for (int q = 0; q < 4; ++q) {
            const int j = jb + 32 * q;
            const float* xj = &xs[j * 33];
            float d = 0.f;
#pragma unroll
            for (int k = 0; k < 31; ++k) d = fmaf(xi_r[k], xj[k], d);
            ddot[il * 128 + j] = d;
        }
    }
    __syncthreads();
    const int cg_ = tid & 3, eg = tid >> 2;
    float w64r[16], w65r[16];
    {
        const float* wg4 = W1 + 64 * 64 + cg_ * 16;
        const float* wg5 = W1 + 65 * 64 + cg_ * 16;
#pragma unroll
        for (int u = 0; u < 4; ++u) {
            float4 v = *(const float4*)(wg4 + u * 4);
            w64r[4*u] = v.x; w64r[4*u+1] = v.y; w64r[4*u+2] = v.z; w64r[4*u+3] = v.w;
            float4 w = *(const float4*)(wg5 + u * 4);
            w65r[4*u] = w.x; w65r[4*u+1] = w.y; w65r[4*u+2] = w.z; w65r[4*u+3] = w.w;
        }
    }
    float sum[16], sq[16];
#pragma unroll
    for (int u = 0; u < 16; ++u) { sum[u] = 0.f; sq[u] = 0.f; }
    for (int ei = 0; ei < 16; ++ei) {
        const int eid = eg + 64 * ei;
        const int il = eid >> 7, j = eid & 127;
        const float2 nj = nls[j];
        const float2 ni = nls[ibase + il];
        const float dot = ddot[il * 128 + j];
        const float dist = sqrtf(fmaxf(ni.x + nj.x - 2.f * dot, 0.f));
        const float itf = 1.f - (nj.y - ni.y);
        const int prow = __builtin_amdgcn_readfirstlane((b * 128 + ibase + il) * 64) + cg_ * 16;
        const float* p2row = P2 + (b * 128 + j) * 64 + cg_ * 16;
#pragma unroll
        for (int u = 0; u < 4; ++u) {
            const float4 p1v = *(const float4*)(P1 + prow + u * 4);
            const float4 p2v = *(const float4*)(p2row + u * 4);
            float y0 = fmaf(itf, w65r[4*u+0], fmaf(dist, w64r[4*u+0], p1v.x + p2v.x));
            float y1 = fmaf(itf, w65r[4*u+1], fmaf(dist, w64r[4*u+1], p1v.y + p2v.y));
            float y2 = fmaf(itf, w65r[4*u+2], fmaf(dist, w64r[4*u+2], p1v.z + p2v.z));
            float y3 = fmaf(itf, w65r[4*u+3], fmaf(dist, w64r[4*u+3], p1v.w + p2v.w));
            y0 = LRELU(y0); y1 = LRELU(y1); y2 = LRELU(y2); y3 = LRELU(y3);
            sum[4*u+0] += y0; sq[4*u+0] += y0 * y0;
            sum[4*u+1] += y1; sq[4*u+1] += y1 * y1;
            sum[4*u+2] += y2; sq[4*u+2] += y2 * y2;
            sum[4*u+3] += y3; sq[4*u+3] += y3 * y3;
        }
    }
#pragma unroll
    for (int u = 0; u < 16; ++u) {
        float s = sum[u], q = sq[u];
#pragma unroll
        for (int m = 4; m < 64; m <<= 1) { s += __shfl_xor(s, m, 64); q += __shfl_xor(q, m, 64); }
        sum[u] = s; sq[u] = q;
    }
    const int l = tid & 63, w = tid >> 6;
#pragma unroll
    for (int k = 0; k < 16; ++k) {
        if ((l >> 2) == k) {
            red[w * 128 + cg_ * 32 + k] = sum[k];
            red[w * 128 + cg_ * 32 + 16 + k] = sq[k];
        }
    }
    __syncthreads();
    if (tid < 128) {
        const float t = red[tid] + red[128 + tid] + red[256 + tid] + red[384 + tid];
        const int cgf = tid >> 5, r = tid & 31;
        if (r < 16) atomicAdd(stA + cgf * 16 + r, t);
        else        atomicAdd(stA + 64 + cgf * 16 + (r - 16), t);
    }
}

// ---------------- fold: wa/wb/b2' (f32) + W2' hi/lo bf16 B-fragment order ----
__global__ __launch_bounds__(256) void k_fold(const float* __restrict__ stA,
                                              const float* __restrict__ g1,
                                              const float* __restrict__ bt1,
                                              const float* __restrict__ W1,
                                              const float* __restrict__ W2,
                                              const float* __restrict__ b2g,
                                              float* __restrict__ wf,
                                              unsigned short* __restrict__ wfb) {
    __shared__ float s1[64], t1[64];
    const int tid = threadIdx.x;
    if (tid < 64) {
        const float ic = 1.f / 1048576.f;
        const float mu = stA[tid] * ic;
        const float var = stA[64 + tid] * ic - mu * mu;
        const float sv = g1[tid] * rsqrtf(var + BN_EPS);
        s1[tid] = sv;
        t1[tid] = bt1[tid] - mu * sv;
        wf[tid] = W1[64 * 64 + tid];
        wf[64 + tid] = W1[65 * 64 + tid];
    }
    __syncthreads();
    if (tid < 32) {
        float acc = b2g[tid];
#pragma unroll
        for (int k = 0; k < 64; ++k) acc = fmaf(t1[k], W2[k * 32 + tid], acc);
        wf[128 + tid] = acc;
    }
    {
        const int ks2n = tid >> 6, L = tid & 63;
        const int ks = ks2n >> 1, n = ks2n & 1;
#pragma unroll
        for (int e = 0; e < 8; ++e) {
            const int k = (L >> 4) * 8 + e + 32 * ks;
            const int col = n * 16 + (L & 15);
            const float wv = W2[k * 32 + col] * s1[k];
            const unsigned short hi = bf16rne(wv);
            const unsigned short lo = bf16rne(wv - bf16tof(hi));
            wfb[(ks2n * 64 + L) * 8 + e] = hi;
            wfb[8192 + (ks2n * 64 + L) * 8 + e] = lo;
        }
    }
}

// ---------------- edge pass 2: layer1 (fp32) -> split-bf16 LDS -> MFMA -> aggregate ----
__global__ __launch_bounds__(256) void k_edge2(const float* __restrict__ xc,
                                               const float2* __restrict__ nbuf,
                                               const float* __restrict__ P1,
                                               const float* __restrict__ P2,
                                               const float* __restrict__ wf,
                                               const unsigned short* __restrict__ wfb,
                                               float* __restrict__ stB,
                                               float* __restrict__ aggp) {
    __shared__ __align__(16) char smem_u[32768];     // xs (dot) / ytile hi(16KB)+lo(16KB)
    __shared__ float ddot[1024];
    __shared__ float2 nls[128];
    __shared__ float cb[4][64];
    __shared__ float aggl[256];
    __shared__ float sqil[256];
    float* xs = (float*)smem_u;
    unsigned short* ytile = (unsigned short*)smem_u;  // hi: 8x[16][64]; lo at +8192
    const int tid = threadIdx.x;
    const int b = blockIdx.x >> 4;
    const int ibase = (blockIdx.x & 15) * 8;
    const float* xg = xc + b * 4096;
    for (int u = tid; u < 4096; u += 256) xs[(u >> 5) * 33 + (u & 31)] = xg[u];
    if (tid < 128) nls[tid] = nbuf[b * 128 + tid];
    __syncthreads();
    {   // dot phase
        const int il = tid >> 5, jb = tid & 31;
        const float* xi = &xs[(ibase + il) * 33];
        float xi_r[31];
#pragma unroll
        for (int k = 0; k < 31; ++k) xi_r[k] = xi[k];
        for (int q = 0; q < 4; ++q) {
            const int j = jb + 32 * q;
            const float* xj = &xs[j * 33];
            float d = 0.f;
#pragma unroll
            for (int k = 0; k < 31; ++k) d = fmaf(xi_r[k], xj[k], d);
            ddot[il * 128 + j] = d;
        }
    }
    const int w = tid >> 6, l = tid & 63;
    short8v bfh[2][2], bfl[2][2];
#pragma unroll
    for (int ks = 0; ks < 2; ++ks)
#pragma unroll
        for (int n = 0; n < 2; ++n) {
            bfh[ks][n] = *(const short8v*)(wfb + ((ks * 2 + n) * 64 + l) * 8);
            bfl[ks][n] = *(const short8v*)(wfb + 8192 + ((ks * 2 + n) * 64 + l) * 8);
        }
    const float b2p0 = wf[128 + (l & 15)];
    const float b2p1 = wf[144 + (l & 15)];
    const int tq = tid & 127;
    const int ch = (tid >> 7) * 32;
    const int r = tq & 15;
    const int tl = tq >> 4;
    __syncthreads();                     // xs dead -> ytile reuse

#pragma unroll 1
    for (int c = 0; c < 8; ++c) {
        // ---- phase A: build y tile hi/lo for il = c ----
        {
            const float2 ni = nls[ibase + c];
            const float2 nj = nls[tq];
            const float dot = ddot[c * 128 + tq];
            const float dist = sqrtf(fmaxf(ni.x + nj.x - 2.f * dot, 0.f));
            const float itf = 1.f - (nj.y - ni.y);
            const float* p1r = P1 + (b * 128 + ibase + c) * 64 + ch;
            const float* p2r = P2 + (b * 128 + tq) * 64 + ch;
            const float* war = wf + ch;
            const float* wbr = wf + 64 + ch;
            unsigned int pkh[16], pkl[16];
#pragma unroll
            for (int u = 0; u < 8; ++u) {
                const float4 p1v = *(const float4*)(p1r + u * 4);
                const float4 p2v = *(const float4*)(p2r + u * 4);
                const float4 wa = *(const float4*)(war + u * 4);
                const float4 wb = *(const float4*)(wbr + u * 4);
                float y0 = fmaf(itf, wb.x, fmaf(dist, wa.x, p1v.x + p2v.x));
                float y1 = fmaf(itf, wb.y, fmaf(dist, wa.y, p1v.y + p2v.y));
                float y2 = fmaf(itf, wb.z, fmaf(dist, wa.z, p1v.z + p2v.z));
                float y3 = fmaf(itf, wb.w, fmaf(dist, wa.w, p1v.w + p2v.w));
                y0 = LRELU(y0); y1 = LRELU(y1); y2 = LRELU(y2); y3 = LRELU(y3);
                const unsigned short h0 = bf16rne(y0), h1 = bf16rne(y1);
                const unsigned short h2 = bf16rne(y2), h3 = bf16rne(y3);
                const unsigned short lo0 = bf16rne(y0 - bf16tof(h0));
                const unsigned short lo1 = bf16rne(y1 - bf16tof(h1));
                const unsigned short lo2 = bf16rne(y2 - bf16tof(h2));
                const unsigned short lo3 = bf16rne(y3 - bf16tof(h3));
                pkh[u * 2]     = (unsigned int)h0 | ((unsigned int)h1 << 16);
                pkh[u * 2 + 1] = (unsigned int)h2 | ((unsigned int)h3 << 16);
                pkl[u * 2]     = (unsigned int)lo0 | ((unsigned int)lo1 << 16);
                pkl[u * 2 + 1] = (unsigned int)lo2 | ((unsigned int)lo3 << 16);
            }
            unsigned short* tbh = ytile + tl * 1024;
            unsigned short* tbl = ytile + 8192 + tl * 1024;
#pragma unroll
            for (int s = 0; s < 4; ++s) {
                const int kb = (ch >> 3) + s;
                const int offu = r * 64 + ((kb ^ (r & 7)) << 3);
                *(int4*)(tbh + offu) = make_int4((int)pkh[4*s], (int)pkh[4*s+1],
                                                 (int)pkh[4*s+2], (int)pkh[4*s+3]);
                *(int4*)(tbl + offu) = make_int4((int)pkl[4*s], (int)pkl[4*s+1],
                                                 (int)pkl[4*s+2], (int)pkl[4*s+3]);
            }
        }
        __syncthreads();
        // ---- phase B: 3-product MFMA over this il's 8 M-tiles (2 per wave) ----
        float aggA0 = 0.f, aggA1 = 0.f, sqA0 = 0.f, sqA1 = 0.f;
#pragma unroll
        for (int q = 0; q < 2; ++q) {
            const int T = w * 2 + q;
            const unsigned short* tbh = ytile + T * 1024;
            const unsigned short* tbl = ytile + 8192 + T * 1024;
            const int row = l & 15, kg = l >> 4;
            const int off0 = row * 64 + ((kg ^ (row & 7)) << 3);
            const int off1 = row * 64 + (((kg + 4) ^ (row & 7)) << 3);
            const short8v a0h = *(const short8v*)(tbh + off0);
            const short8v a1h = *(const short8v*)(tbh + off1);
            const short8v a0l = *(const short8v*)(tbl + off0);
            const short8v a1l = *(const short8v*)(tbl + off1);
            f32x4 acc0 = {0.f, 0.f, 0.f, 0.f};
            f32x4 acc1 = {0.f, 0.f, 0.f, 0.f};
            acc0 = __builtin_amdgcn_mfma_f32_16x16x32_bf16(a0h, bfh[0][0], acc0, 0, 0, 0);
            acc0 = __builtin_amdgcn_mfma_f32_16x16x32_bf16(a0h, bfl[0][0], acc0, 0, 0, 0);
            acc0 = __builtin_amdgcn_mfma_f32_16x16x32_bf16(a0l, bfh[0][0], acc0, 0, 0, 0);
            acc0 = __builtin_amdgcn_mfma_f32_16x16x32_bf16(a1h, bfh[1][0], acc0, 0, 0, 0);
            acc0 = __builtin_amdgcn_mfma_f32_16x16x32_bf16(a1h, bfl[1][0], acc0, 0, 0, 0);
            acc0 = __builtin_amdgcn_mfma_f32_16x16x32_bf16(a1l, bfh[1][0], acc0, 0, 0, 0);
            acc1 = __builtin_amdgcn_mfma_f32_16x16x32_bf16(a0h, bfh[0][1], acc1, 0, 0, 0);
            acc1 = __builtin_amdgcn_mfma_f32_16x16x32_bf16(a0h, bfl[0][1], acc1, 0, 0, 0);
            acc1 = __builtin_amdgcn_mfma_f32_16x16x32_bf16(a0l, bfh[0][1], acc1, 0, 0, 0);
            acc1 = __builtin_amdgcn_mfma_f32_16x16x32_bf16(a1h, bfh[1][1], acc1, 0, 0, 0);
            acc1 = __builtin_amdgcn_mfma_f32_16x16x32_bf16(a1h, bfl[1][1], acc1, 0, 0, 0);
            acc1 = __builtin_amdgcn_mfma_f32_16x16x32_bf16(a1l, bfh[1][1], acc1, 0, 0, 0);
            float s0 = 0.f, q0 = 0.f, s1 = 0.f, q1 = 0.f;
#pragma unroll
            for (int r4 = 0; r4 < 4; ++r4) {
                const float z0 = LRELU(acc0[r4] + b2p0);
                const float z1 = LRELU(acc1[r4] + b2p1);
                s0 += z0; q0 += z0 * z0;
                s1 += z1; q1 += z1 * z1;
            }
            s0 += __shfl_xor(s0, 16, 64); s0 += __shfl_xor(s0, 32, 64);
            q0 += __shfl_xor(q0, 16, 64); q0 += __shfl_xor(q0, 32, 64);
            s1 += __shfl_xor(s1, 16, 64); s1 += __shfl_xor(s1, 32, 64);
            q1 += __shfl_xor(q1, 16, 64); q1 += __shfl_xor(q1, 32, 64);
            aggA0 += s0; sqA0 += q0;
            aggA1 += s1; sqA1 += q1;
        }
        if (l < 16) {
            cb[w][l] = aggA0;      cb[w][16 + l] = aggA1;
            cb[w][32 + l] = sqA0;  cb[w][48 + l] = sqA1;
        }
        __syncthreads();
        if (tid < 32) {
            aggl[c * 32 + tid] = cb[0][tid] + cb[1][tid] + cb[2][tid] + cb[3][tid];
            sqil[c * 32 + tid] = cb[0][32 + tid] + cb[1][32 + tid]
                               + cb[2][32 + tid] + cb[3][32 + tid];
        }
    }
    __syncthreads();
    {
        const int il2 = tid >> 5, c2 = tid & 31;
        aggp[(b * 128 + ibase + il2) * 32 + c2] = aggl[il2 * 32 + c2];
    }
    if (tid < 32) {
        float s = 0.f, qq = 0.f;
#pragma unroll
        for (int il3 = 0; il3 < 8; ++il3) { s += aggl[il3 * 32 + tid]; qq += sqil[il3 * 32 + tid]; }
        atomicAdd(stB + tid, s);
        atomicAdd(stB + 32 + tid, qq);
    }
}

// ---------------- software grid barrier (all blocks co-resident) ----------------
__device__ __forceinline__ void gbar(unsigned int* ctr, unsigned int target) {
    __syncthreads();
    if (threadIdx.x == 0) {
        __hip_atomic_fetch_add(ctr, 1u, __ATOMIC_ACQ_REL, __HIP_MEMORY_SCOPE_AGENT);
        while (__hip_atomic_load(ctr, __ATOMIC_ACQUIRE, __HIP_MEMORY_SCOPE_AGENT) < target) {
            __builtin_amdgcn_s_sleep(2);
        }
    }
    __syncthreads();
}

// ---------------- fused node MLP: L1 -> BN -> L2 -> BN -> tanh(Wu) + prep ----
__global__ __launch_bounds__(256) void k_nodeF(
    const float* __restrict__ aggp, const float* __restrict__ xc,
    const float* __restrict__ W0, const float* __restrict__ b0,
    const float* __restrict__ stB, const float* __restrict__ g2, const float* __restrict__ bt2,
    const float* __restrict__ W1m, const float* __restrict__ b1m,
    float* __restrict__ stC, const float* __restrict__ gC, const float* __restrict__ btC,
    const float* __restrict__ W2m, const float* __restrict__ b2m,
    float* __restrict__ stD, const float* __restrict__ gD, const float* __restrict__ btD,
    float* __restrict__ xout,
    const float* __restrict__ W1n, const float* __restrict__ b1n,
    float* __restrict__ P1, float* __restrict__ P2, float2* __restrict__ nbuf,
    unsigned int* __restrict__ bar, int doPrep)
{
    __shared__ float w0s[2048];
    __shared__ float wms[1024];
    __shared__ float wus[1024];
    __shared__ float w1s[4096];
    __shared__ float b0s[32], s2s[32], t2s[32];
    __shared__ float bms[32], sCs[32], tCs[32];
    __shared__ float bus[32], sDs[32], tDs[32];
    __shared__ float b1s[64];
    __shared__ float red[256];
    const int tid = threadIdx.x;
    const int row = blockIdx.x * 256 + tid;
    for (int k = tid; k < 2048; k += 256) w0s[k] = W0[k];
    for (int k = tid; k < 1024; k += 256) { wms[k] = W1m[k]; wus[k] = W2m[k]; }
    if (doPrep) {
        for (int k = tid; k < 4096; k += 256) w1s[k] = W1n[k];
        if (tid < 64) b1s[tid] = b1n[tid];
    }
    if (tid < 32) {
        b0s[tid] = b0[tid]; bms[tid] = b1m[tid]; bus[tid] = b2m[tid];
        const float ic = 1.f / 1048576.f;
        const float mu = stB[tid] * ic;
        const float var = stB[32 + tid] * ic - mu * mu;
        const float sv = g2[tid] * rsqrtf(var + BN_EPS);
        s2s[tid] = sv; t2s[tid] = bt2[tid] - mu * sv;
    }
    __syncthreads();
    float h[64];
    {
        const float4* ap = (const float4*)(aggp + row * 32);
        const float4* xp = (const float4*)(xc + row * 32);
#pragma unroll
        for (int u = 0; u < 8; ++u) {
            const float4 a = ap[u];
            h[4*u+0] = fmaf(s2s[4*u+0], a.x, 128.f * t2s[4*u+0]);
            h[4*u+1] = fmaf(s2s[4*u+1], a.y, 128.f * t2s[4*u+1]);
            h[4*u+2] = fmaf(s2s[4*u+2], a.z, 128.f * t2s[4*u+2]);
            h[4*u+3] = fmaf(s2s[4*u+3], a.w, 128.f * t2s[4*u+3]);
            const float4 xv = xp[u];
            h[32+4*u+0] = xv.x; h[32+4*u+1] = xv.y; h[32+4*u+2] = xv.z; h[32+4*u+3] = xv.w;
        }
    }
    float v[32];
#pragma unroll
    for (int o0 = 0; o0 < 32; o0 += 4) {
        float z0 = b0s[o0], z1 = b0s[o0+1], z2 = b0s[o0+2], z3 = b0s[o0+3];
#pragma unroll
        for (int k = 0; k < 64; ++k) {
            const float4 wv = *(const float4*)&w0s[k * 32 + o0];
            const float hv = h[k];
            z0 = fmaf(hv, wv.x, z0); z1 = fmaf(hv, wv.y, z1);
            z2 = fmaf(hv, wv.z, z2); z3 = fmaf(hv, wv.w, z3);
        }
        v[o0] = LRELU(z0); v[o0+1] = LRELU(z1); v[o0+2] = LRELU(z2); v[o0+3] = LRELU(z3);
    }
    {
        float sarr[32], qarr[32];
#pragma unroll
        for (int o = 0; o < 32; ++o) {
            float s = v[o], q = v[o] * v[o];
#pragma unroll
            for (int m = 1; m < 64; m <<= 1) { s += __shfl_xor(s, m, 64); q += __shfl_xor(q, m, 64); }
            sarr[o] = s; qarr[o] = q;
        }
        const int lane = tid & 63, wid = tid >> 6;
        if (lane == 0) {
#pragma unroll
            for (int o = 0; o < 32; ++o) { red[wid * 64 + o] = sarr[o]; red[wid * 64 + 32 + o] = qarr[o]; }
        }
        __syncthreads();
        if (tid < 64) {
            const float t = red[tid] + red[64 + tid] + red[128 + tid] + red[192 + tid];
            atomicAdd(stC + tid, t);
        }
    }
    gbar(bar + 0, 32);
    if (tid < 32) {
        const float ic = 1.f / 8192.f;
        const float mu = __hip_atomic_load(stC + tid, __ATOMIC_RELAXED, __HIP_MEMORY_SCOPE_AGENT) * ic;
        const float sq = __hip_atomic_load(stC + 32 + tid, __ATOMIC_RELAXED, __HIP_MEMORY_SCOPE_AGENT) * ic;
        const float var = sq - mu * mu;
        const float sv = gC[tid] * rsqrtf(var + BN_EPS);
        sCs[tid] = sv; tCs[tid] = btC[tid] - mu * sv;
    }
    __syncthreads();
    float hh[32];
#pragma unroll
    for (int c = 0; c < 32; ++c) hh[c] = fmaf(sCs[c], v[c], tCs[c]);
    float v2[32];
#pragma unroll
    for (int o0 = 0; o0 < 32; o0 += 4) {
        float z0 = bms[o0], z1 = bms[o0+1], z2 = bms[o0+2], z3 = bms[o0+3];
#pragma unroll
        for (int k = 0; k < 32; ++k) {
            const float4 wv = *(const float4*)&wms[k * 32 + o0];
            const float hv = hh[k];
            z0 = fmaf(hv, wv.x, z0); z1 = fmaf(hv, wv.y, z1);
            z2 = fmaf(hv, wv.z, z2); z3 = fmaf(hv, wv.w, z3);
        }
        v2[o0] = LRELU(z0); v2[o0+1] = LRELU(z1); v2[o0+2] = LRELU(z2); v2[o0+3] = LRELU(z3);
    }
    {
        float sarr[32], qarr[32];
#pragma unroll
        for (int o = 0; o < 32; ++o) {
            float s = v2[o], q = v2[o] * v2[o];
#pragma unroll
            for (int m = 1; m < 64; m <<= 1) { s += __shfl_xor(s, m, 64); q += __shfl_xor(q, m, 64); }
            sarr[o] = s; qarr[o] = q;
        }
        const int lane = tid & 63, wid = tid >> 6;
        __syncthreads();
        if (lane == 0) {
#pragma unroll
            for (int o = 0; o < 32; ++o) { red[wid * 64 + o] = sarr[o]; red[wid * 64 + 32 + o] = qarr[o]; }
        }
        __syncthreads();
        if (tid < 64) {
            const float t = red[tid] + red[64 + tid] + red[128 + tid] + red[192 + tid];
            atomicAdd(stD + tid, t);
        }
    }
    gbar(bar + 1, 32);
    if (tid < 32) {
        const float ic = 1.f / 8192.f;
        const float mu = __hip_atomic_load(stD + tid, __ATOMIC_RELAXED, __HIP_MEMORY_SCOPE_AGENT) * ic;
        const float sq = __hip_atomic_load(stD + 32 + tid, __ATOMIC_RELAXED, __HIP_MEMORY_SCOPE_AGENT) * ic;
        const float var = sq - mu * mu;
        const float sv = gD[tid] * rsqrtf(var + BN_EPS);
        sDs[tid] = sv; tDs[tid] = btD[tid] - mu * sv;
    }
    __syncthreads();
    float h3[32];
#pragma unroll
    for (int c = 0; c < 32; ++c) h3[c] = fmaf(sDs[c], v2[c], tDs[c]);
    float xn[32];
    float* xp = xout + row * 32;
#pragma unroll
    for (int o0 = 0; o0 < 32; o0 += 4) {
        float z0 = bus[o0], z1 = bus[o0+1], z2 = bus[o0+2], z3 = bus[o0+3];
#pragma unroll
        for (int k = 0; k < 32; ++k) {
            const float4 wv = *(const float4*)&wus[k * 32 + o0];
            const float hv = h3[k];
            z0 = fmaf(hv, wv.x, z0); z1 = fmaf(hv, wv.y, z1);
            z2 = fmaf(hv, wv.z, z2); z3 = fmaf(hv, wv.w, z3);
        }
        xn[o0]   = tanhf(z0);
        xn[o0+1] = tanhf(z1);
        xn[o0+2] = tanhf(z2);
        xn[o0+3] = tanhf(z3);
        xp[o0] = xn[o0]; xp[o0+1] = xn[o0+1]; xp[o0+2] = xn[o0+2]; xp[o0+3] = xn[o0+3];
    }
    if (!doPrep) return;
    float n = 0.f;
#pragma unroll
    for (int k = 0; k < 31; ++k) n = fmaf(xn[k], xn[k], n);
    nbuf[row] = make_float2(n, xn[31]);
    float* p1p = P1 + row * 64;
    float* p2p = P2 + row * 64;
#pragma unroll
    for (int c0 = 0; c0 < 64; c0 += 4) {
        float a0 = b1s[c0], a1 = b1s[c0+1], a2 = b1s[c0+2], a3 = b1s[c0+3];
        float q0 = 0.f, q1 = 0.f, q2 = 0.f, q3 = 0.f;
#pragma unroll
        for (int k = 0; k < 32; ++k) {
            const float xv = xn[k];
            const float4 wa = *(const float4*)&w1s[k * 64 + c0];
            const float4 wb = *(const float4*)&w1s[(32 + k) * 64 + c0];
            a0 = fmaf(xv, wa.x, a0); a1 = fmaf(xv, wa.y, a1);
            a2 = fmaf(xv, wa.z, a2); a3 = fmaf(xv, wa.w, a3);
            q0 = fmaf(xv, wb.x, q0); q1 = fmaf(xv, wb.y, q1);
            q2 = fmaf(xv, wb.z, q2); q3 = fmaf(xv, wb.w, q3);
        }
        p1p[c0] = a0; p1p[c0+1] = a1; p1p[c0+2] = a2; p1p[c0+3] = a3;
        p2p[c0] = q0; p2p[c0+1] = q1; p2p[c0+2] = q2; p2p[c0+3] = q3;
    }
}

extern "C" void kernel_launch(void* const* d_in, const int* in_sizes, int n_in,
                              void* d_out, int out_size, void* d_ws, size_t ws_size,
                              hipStream_t stream) {
    const float* x    = (const float*)d_in[0];
    const float* Wah  = (const float*)d_in[1];
    const float* bah  = (const float*)d_in[2];
    const float* Wa   = (const float*)d_in[3];
    const float* ba   = (const float*)d_in[4];
    const float* g_eh = (const float*)d_in[5];
    const float* b_eh = (const float*)d_in[6];
    const float* g_e  = (const float*)d_in[7];
    const float* b_e  = (const float*)d_in[8];
    const float* Wn0  = (const float*)d_in[9];
    const float* bn0  = (const float*)d_in[10];
    const float* Wn   = (const float*)d_in[11];
    const float* bnn  = (const float*)d_in[12];
    const float* g_n  = (const float*)d_in[13];
    const float* b_n  = (const float*)d_in[14];
    const float* Wu   = (const float*)d_in[15];
    const float* bu   = (const float*)d_in[16];

    float* ws    = (float*)d_ws;
    float* xc    = ws;                 // 262144
    float* aggp  = ws + 262144;        // 262144
    float* P1    = ws + 786432;        // 524288
    float* P2    = ws + 1310720;       // 524288
    float2* nbuf = (float2*)(ws + 1835008);  // 16384 float2
    float* stats = ws + 1867776;       // 1280 (320/step)
    unsigned int* bar = (unsigned int*)(ws + 1869056);  // 16 counters
    float* wf    = ws + 1869072;       // 160 floats (wa|wb|b2')
    unsigned short* wfb = (unsigned short*)(ws + 1869232);  // 16384 bf16 (hi|lo)
    float* out   = (float*)d_out;

    hipMemsetAsync(stats, 0, (1280 + 16) * sizeof(float), stream);
    k_pad_prep<<<64, 128, 0, stream>>>(x, Wah, bah, xc, P1, P2, nbuf);

    for (int s = 0; s < 4; ++s) {
        const float* W1 = Wah + s * 66 * 64;
        const float* W2 = Wa + s * 64 * 32;
        const float* b2 = ba + s * 32;
        float* stA = stats + s * 320;
        float* stB = stA + 128;
        float* stC = stA + 192;
        float* stD = stA + 256;

        k_edge1<<<1024, 256, 0, stream>>>(xc, nbuf, P1, P2, W1, stA);
        k_fold<<<1, 256, 0, stream>>>(stA, g_eh + s * 64, b_eh + s * 64, W1, W2, b2, wf, wfb);
        k_edge2<<<1024, 256, 0, stream>>>(xc, nbuf, P1, P2, wf, wfb, stB, aggp);
        k_nodeF<<<32, 256, 0, stream>>>(aggp, xc, Wn0 + s * 2048, bn0 + s * 32,
                                        stB, g_e + s * 32, b_e + s * 32,
                                        Wn + s * 1024, bnn + s * 32,
                                        stC, g_n + s * 64, b_n + s * 64,
                                        Wu + s * 1024, bu + s * 32,
                                        stD, g_n + s * 64 + 32, b_n + s * 64 + 32,
                                        (s == 3) ? out : xc,
                                        (s < 3) ? (Wah + (s + 1) * 66 * 64) : Wah,
                                        (s < 3) ? (bah + (s + 1) * 64) : bah,
                                        P1, P2, nbuf, bar + s * 2, (s < 3) ? 1 : 0);
    }
}